// Round 7
// baseline (278.078 us; speedup 1.0000x reference)
//
#include <hip/hip_runtime.h>
#include <hip/hip_bf16.h>
#include <math.h>

#define B_  2
#define S_  2048
#define D_  1024
#define H_  16
#define DH_ 64
#define M_  (B_ * S_)   // 4096 tokens

typedef __attribute__((ext_vector_type(8))) short bf16x8;  // 8 bf16 (4 VGPRs)
typedef __attribute__((ext_vector_type(4))) short bf16x4;  // 4 bf16 (2 VGPRs)
typedef __attribute__((ext_vector_type(4))) float f32x4;   // MFMA C/D frag

#if __has_builtin(__builtin_amdgcn_mfma_f32_16x16x16bf16_1k)
#define HAVE_MFMA16 1
#define MFMA16(a, b, c) __builtin_amdgcn_mfma_f32_16x16x16bf16_1k(a, b, c, 0, 0, 0)
#else
#define HAVE_MFMA16 0
#endif

__device__ __forceinline__ float fast_exp2(float x) {
  return __builtin_amdgcn_exp2f(x);   // v_exp_f32
}

__device__ __forceinline__ unsigned short f2bf(float f) {
  union { float f; unsigned u; } c; c.f = f;
  unsigned u = c.u;
  return (unsigned short)((u + 0x7FFFu + ((u >> 16) & 1u)) >> 16);  // RNE
}

// pack two floats -> two bf16 (round-half-up) in one dword via v_perm
__device__ __forceinline__ unsigned pkbf(float lo, float hi) {
  union { float f; unsigned u; } a, b;
  a.f = lo; b.f = hi;
  return __builtin_amdgcn_perm(b.u + 0x8000u, a.u + 0x8000u, 0x07060302u);
}

__device__ __forceinline__ float logsig(float x) {
  return fminf(x, 0.f) - log1pf(__expf(-fabsf(x)));   // stable log_sigmoid
}

// XOR-swizzled LDS index: rows of 64 shorts (8 chunks of 8); chunk ^= row&7.
__device__ __forceinline__ int swz(int row, int col) {
  return (row << 6) + ((((col >> 3) ^ row) & 7) << 3) + (col & 7);
}

// ---------------------------------------------------------------------------
// Kernel 0a: hs fp32 [M][D] -> bf16 hsb (streaming, coalesced)
// ---------------------------------------------------------------------------
__global__ __launch_bounds__(256) void prep_hs(
    const float* __restrict__ hs, unsigned short* __restrict__ hsb)
{
  const int nvec = M_ * D_ / 4;
  for (int i = blockIdx.x * 256 + threadIdx.x; i < nvec; i += gridDim.x * 256) {
    const float4 v = *(const float4*)&hs[(size_t)i * 4];
    uint2 u;
    u.x = pkbf(v.x, v.y);
    u.y = pkbf(v.z, v.w);
    *(uint2*)&hsb[(size_t)i * 4] = u;
  }
}

// ---------------------------------------------------------------------------
// Kernel 0b: transpose Wq/Wk (fp32 [K][N]) -> bf16 W^T [N][K]
// ---------------------------------------------------------------------------
__global__ __launch_bounds__(256) void prep_w(
    const float* __restrict__ Wq, const float* __restrict__ Wk,
    unsigned short* __restrict__ WqT, unsigned short* __restrict__ WkT)
{
  __shared__ unsigned short T[64][72];
  const int tid = threadIdx.x;
  const int k0 = blockIdx.x * 64;
  const int n0 = blockIdx.y * 64;
  const float* W = blockIdx.z ? Wk : Wq;
  unsigned short* WT = blockIdx.z ? WkT : WqT;

  const int kr = tid >> 2, nc = (tid & 3) * 16;
  #pragma unroll
  for (int i = 0; i < 4; i++) {
    const float4 v = *(const float4*)&W[(size_t)(k0 + kr) * D_ + n0 + nc + i * 4];
    T[nc + i * 4 + 0][kr] = f2bf(v.x);
    T[nc + i * 4 + 1][kr] = f2bf(v.y);
    T[nc + i * 4 + 2][kr] = f2bf(v.z);
    T[nc + i * 4 + 3][kr] = f2bf(v.w);
  }
  __syncthreads();
  const int nr = tid >> 2, kc = (tid & 3) * 16;
  const uint4 a = *(const uint4*)&T[nr][kc];
  const uint4 b = *(const uint4*)&T[nr][kc + 8];
  *(uint4*)&WT[(size_t)(n0 + nr) * D_ + k0 + kc] = a;
  *(uint4*)&WT[(size_t)(n0 + nr) * D_ + k0 + kc + 8] = b;
}

// ---------------------------------------------------------------------------
// Kernel 1: Q = hs@Wq+bq ; K2 = logsig(logsig(Q)+Q+hs@Wk+bk)
//   outputs: K2b [M][D] bf16 row-major, QT [H*64][M] bf16 (per-head Q^T)
// R4 structure (best measured): padded-72 LDS (36.9 KB -> 3-4 blocks/CU),
// simple 2-barrier K-loop, no reg prefetch. Only delta vs R4: staging map
// is 8 lanes x 16B = 128B contiguous per row (full-line coalescing).
// ---------------------------------------------------------------------------
__global__ __launch_bounds__(256) void proj_kernel(
    const unsigned short* __restrict__ hsb,
    const unsigned short* __restrict__ WqT, const unsigned short* __restrict__ WkT,
    const float* __restrict__ bqv, const float* __restrict__ bkv,
    unsigned short* __restrict__ K2b, unsigned short* __restrict__ QT)
{
  __shared__ unsigned short Ash[128][72];     // hs tile [m][k]
  __shared__ unsigned short Bsh[2][64][72];   // W^T tiles [n][k]

  const int tid  = threadIdx.x;
  const int w    = tid >> 6;
  const int lane = tid & 63;
  const int quad = lane >> 4;
  const int l16  = lane & 15;
  const int m0 = blockIdx.x * 128;
  const int n0 = blockIdx.y * 64;     // = head * 64

  float bqs[4], bks[4];
  #pragma unroll
  for (int nt = 0; nt < 4; nt++) {
    bqs[nt] = bqv[n0 + nt * 16 + l16];
    bks[nt] = bkv[n0 + nt * 16 + l16];
  }

  f32x4 accQ[2][4], accK[2][4];
  #pragma unroll
  for (int st = 0; st < 2; st++)
    #pragma unroll
    for (int nt = 0; nt < 4; nt++) {
      accQ[st][nt] = (f32x4){0.f, 0.f, 0.f, 0.f};
      accK[st][nt] = (f32x4){0.f, 0.f, 0.f, 0.f};
    }

  // coalesced staging: 8 lanes x 16B = 128B contiguous per row
  const int srow = tid >> 3;            // 0..31
  const int scol = (tid & 7) * 8;       // 0..56

  for (int k0 = 0; k0 < D_; k0 += 64) {
    __syncthreads();
    #pragma unroll
    for (int j = 0; j < 4; j++) {
      const int row = srow + j * 32;    // 0..127
      *(uint4*)&Ash[row][scol] =
          *(const uint4*)&hsb[(size_t)(m0 + row) * D_ + k0 + scol];
    }
    #pragma unroll
    for (int j = 0; j < 2; j++) {
      const int row = srow + j * 32;    // 0..63
      const size_t g = (size_t)(n0 + row) * D_ + k0 + scol;
      *(uint4*)&Bsh[0][row][scol] = *(const uint4*)&WqT[g];
      *(uint4*)&Bsh[1][row][scol] = *(const uint4*)&WkT[g];
    }
    __syncthreads();

    #pragma unroll
    for (int kk = 0; kk < 2; kk++) {
      bf16x8 af[2];
      af[0] = *(const bf16x8*)&Ash[w * 32 + l16][kk * 32 + quad * 8];
      af[1] = *(const bf16x8*)&Ash[w * 32 + 16 + l16][kk * 32 + quad * 8];
      #pragma unroll
      for (int nt = 0; nt < 4; nt++) {
        const bf16x8 bq8 = *(const bf16x8*)&Bsh[0][nt * 16 + l16][kk * 32 + quad * 8];
        const bf16x8 bk8 = *(const bf16x8*)&Bsh[1][nt * 16 + l16][kk * 32 + quad * 8];
        accQ[0][nt] = __builtin_amdgcn_mfma_f32_16x16x32_bf16(af[0], bq8, accQ[0][nt], 0, 0, 0);
        accQ[1][nt] = __builtin_amdgcn_mfma_f32_16x16x32_bf16(af[1], bq8, accQ[1][nt], 0, 0, 0);
        accK[0][nt] = __builtin_amdgcn_mfma_f32_16x16x32_bf16(af[0], bk8, accK[0][nt], 0, 0, 0);
        accK[1][nt] = __builtin_amdgcn_mfma_f32_16x16x32_bf16(af[1], bk8, accK[1][nt], 0, 0, 0);
      }
    }
  }

  __syncthreads();   // K-loop done; reuse Bsh as Qt [64 d][136 m]
  unsigned short* Qt = &Bsh[0][0][0];   // 64*136 = 8704 <= 9216
  #pragma unroll
  for (int st = 0; st < 2; st++) {
    #pragma unroll
    for (int nt = 0; nt < 4; nt++) {
      float qv[4];
      #pragma unroll
      for (int r = 0; r < 4; r++) {
        const float q  = accQ[st][nt][r] + bqs[nt];
        const float kr = accK[st][nt][r] + bks[nt];
        const float k2 = logsig(logsig(q) + q + kr);
        const int m = m0 + w * 32 + st * 16 + quad * 4 + r;
        K2b[(size_t)m * D_ + n0 + nt * 16 + l16] = f2bf(k2);
        qv[r] = q;
      }
      const ushort4 qu = {f2bf(qv[0]), f2bf(qv[1]), f2bf(qv[2]), f2bf(qv[3])};
      *(ushort4*)&Qt[(nt * 16 + l16) * 136 + w * 32 + st * 16 + quad * 4] = qu;
    }
  }
  __syncthreads();
  {
    const int dr = tid >> 2, mc = (tid & 3) * 32;
    #pragma unroll
    for (int i = 0; i < 4; i++) {
      const uint4 v = *(const uint4*)&Qt[dr * 136 + mc + i * 8];
      *(uint4*)&QT[(size_t)(n0 + dr) * M_ + m0 + mc + i * 8] = v;
    }
  }
}

// ---------------------------------------------------------------------------
// Kernel 2: flash attention, S^T formulation, fixed-shift softmax, PV via
// 16x16x16 MFMA with P in registers. 128-thread / 2-wave blocks, 64-q tiles:
// grid 1024 -> 4 blocks/CU, 8 waves/CU in 4 independent barrier domains.
// Prefetch issued AFTER the post-staging barrier (overlaps compute).
// Grid (bh fastest): all q-tiles of one (b,h) -> same XCD -> K2/V L2 reuse.
// ---------------------------------------------------------------------------
__global__ __launch_bounds__(128) void attn_kernel(
    const unsigned short* __restrict__ QT,
    const unsigned short* __restrict__ K2b,
    const int* __restrict__ mask,
    float* __restrict__ out)
{
  __shared__ unsigned short Qa [64 * 64];   // Q  [q][d]    swizzled
  __shared__ unsigned short K2s[64 * 64];   // K2 [key][d]  swizzled
  __shared__ unsigned short Vt [64 * 64];   // V^T [d][key] swizzled
#if !HAVE_MFMA16
  __shared__ unsigned short Psh[2][16][72];
#endif

  const int tid  = threadIdx.x;       // 0..127
  const int w    = tid >> 6;          // 0..1
  const int lane = tid & 63;
  const int quad = lane >> 4;
  const int l16  = lane & 15;

  const int bh = blockIdx.x;          // 0..31 -> XCD bh%8
  const int qt = blockIdx.y;          // 0..31
  const int b = bh >> 4, h = bh & 15;
  const size_t qrow0 = (size_t)b * S_ + (size_t)qt * 64;
  const size_t krow0 = (size_t)b * S_;
  const int hc = h * 64;

  // staging map: 8 lanes x 16B = 128B per row; 16 rows per pass, 4 passes
  const int srow = tid >> 3;          // 0..15
  const int scol = (tid & 7) * 8;     // 0..56

  // stage Qa [q][d] from QT (transpose once per block)
  #pragma unroll
  for (int j = 0; j < 4; j++) {
    const int d = srow + j * 16;      // 0..63
    const uint4 v = *(const uint4*)&QT[((size_t)hc + d) * M_ + qrow0 + scol];
    const unsigned short* p = (const unsigned short*)&v;
    #pragma unroll
    for (int jj = 0; jj < 8; jj++) Qa[swz(scol + jj, d)] = p[jj];
  }
  __syncthreads();

  bf16x8 qfrag[2][2];
  #pragma unroll
  for (int st = 0; st < 2; st++)
    #pragma unroll
    for (int kk = 0; kk < 2; kk++)
      qfrag[st][kk] = *(const bf16x8*)&Qa[swz(w * 32 + st * 16 + l16, kk * 32 + quad * 8)];

  float c2[2], rl[2] = {0.f, 0.f};
  #pragma unroll
  for (int st = 0; st < 2; st++)
    c2[st] = (mask[qrow0 + w * 32 + st * 16 + l16] != 0) ? -0.18033688f : 0.f;

  f32x4 Ot[2][4];
  #pragma unroll
  for (int st = 0; st < 2; st++)
    #pragma unroll
    for (int dt = 0; dt < 4; dt++) Ot[st][dt] = (f32x4){0.f, 0.f, 0.f, 0.f};

  uint4 preK[4], preV[4];
  #pragma unroll
  for (int j = 0; j < 4; j++) {
    const int row = srow + j * 16;
    preK[j] = *(const uint4*)&K2b[(krow0 + row) * (size_t)D_ + hc + scol];
    preV[j] = *(const uint4*)&QT [((size_t)hc + row) * M_ + krow0 + scol];
  }

  for (int kt = 0; kt < S_ / 64; kt++) {
    __syncthreads();   // previous tile consumed
    #pragma unroll
    for (int j = 0; j < 4; j++) {
      const int row = srow + j * 16;
      *(uint4*)&K2s[swz(row, scol)] = preK[j];
      *(uint4*)&Vt [swz(row, scol)] = preV[j];
    }
    __syncthreads();   // nothing in flight -> free drain

    if (kt + 1 < S_ / 64) {   // prefetch overlaps compute
      const size_t koff = (size_t)(kt + 1) * 64;
      #pragma unroll
      for (int j = 0; j < 4; j++) {
        const int row = srow + j * 16;
        preK[j] = *(const uint4*)&K2b[(krow0 + koff + row) * (size_t)D_ + hc + scol];
        preV[j] = *(const uint4*)&QT [((size_t)hc + row) * M_ + krow0 + koff + scol];
      }
    }

    bf16x8 k2f[4][2];
    #pragma unroll
    for (int nt = 0; nt < 4; nt++)
      #pragma unroll
      for (int kk = 0; kk < 2; kk++)
        k2f[nt][kk] = *(const bf16x8*)&K2s[swz(nt * 16 + l16, kk * 32 + quad * 8)];

#if HAVE_MFMA16
    bf16x4 vf[4][4];   // [dt][nt]: A-frag of V^T for 16x16x16
    #pragma unroll
    for (int dt = 0; dt < 4; dt++)
      #pragma unroll
      for (int nt = 0; nt < 4; nt++)
        vf[dt][nt] = *(const bf16x4*)&Vt[swz(dt * 16 + l16, nt * 16 + quad * 4)];

    #pragma unroll
    for (int st = 0; st < 2; st++) {
      f32x4 sc[4];
      #pragma unroll
      for (int nt = 0; nt < 4; nt++) sc[nt] = (f32x4){0.f, 0.f, 0.f, 0.f};
      #pragma unroll
      for (int kk = 0; kk < 2; kk++)
        #pragma unroll
        for (int nt = 0; nt < 4; nt++)
          sc[nt] = __builtin_amdgcn_mfma_f32_16x16x32_bf16(k2f[nt][kk], qfrag[st][kk], sc[nt], 0, 0, 0);

      #pragma unroll
      for (int nt = 0; nt < 4; nt++) {
        const float p0 = fast_exp2(fmaf(sc[nt][0], c2[st], -12.f));
        const float p1 = fast_exp2(fmaf(sc[nt][1], c2[st], -12.f));
        const float p2 = fast_exp2(fmaf(sc[nt][2], c2[st], -12.f));
        const float p3 = fast_exp2(fmaf(sc[nt][3], c2[st], -12.f));
        rl[st] += (p0 + p1) + (p2 + p3);
        union { unsigned u[2]; bf16x4 v; } pc;
        pc.u[0] = pkbf(p0, p1);
        pc.u[1] = pkbf(p2, p3);
        #pragma unroll
        for (int dt = 0; dt < 4; dt++)
          Ot[st][dt] = MFMA16(vf[dt][nt], pc.v, Ot[st][dt]);
      }
    }
#else
    bf16x8 vf8[4][2];
    #pragma unroll
    for (int dt = 0; dt < 4; dt++)
      #pragma unroll
      for (int kk = 0; kk < 2; kk++)
        vf8[dt][kk] = *(const bf16x8*)&Vt[swz(dt * 16 + l16, kk * 32 + quad * 8)];

    #pragma unroll
    for (int st = 0; st < 2; st++) {
      f32x4 sc[4];
      #pragma unroll
      for (int nt = 0; nt < 4; nt++) sc[nt] = (f32x4){0.f, 0.f, 0.f, 0.f};
      #pragma unroll
      for (int kk = 0; kk < 2; kk++)
        #pragma unroll
        for (int nt = 0; nt < 4; nt++)
          sc[nt] = __builtin_amdgcn_mfma_f32_16x16x32_bf16(k2f[nt][kk], qfrag[st][kk], sc[nt], 0, 0, 0);

      #pragma unroll
      for (int nt = 0; nt < 4; nt++) {
        const float p0 = fast_exp2(fmaf(sc[nt][0], c2[st], -12.f));
        const float p1 = fast_exp2(fmaf(sc[nt][1], c2[st], -12.f));
        const float p2 = fast_exp2(fmaf(sc[nt][2], c2[st], -12.f));
        const float p3 = fast_exp2(fmaf(sc[nt][3], c2[st], -12.f));
        rl[st] += (p0 + p1) + (p2 + p3);
        const uint2 pk = {pkbf(p0, p1), pkbf(p2, p3)};
        *(uint2*)&Psh[w][l16][nt * 16 + quad * 4] = pk;
      }
      #pragma unroll
      for (int kk = 0; kk < 2; kk++) {
        const bf16x8 pf = *(const bf16x8*)&Psh[w][l16][kk * 32 + quad * 8];
        #pragma unroll
        for (int dt = 0; dt < 4; dt++)
          Ot[st][dt] = __builtin_amdgcn_mfma_f32_16x16x32_bf16(vf8[dt][kk], pf, Ot[st][dt], 0, 0, 0);
      }
    }
#endif
  }

  // final row-sum across quads, then write O^T / l
  #pragma unroll
  for (int st = 0; st < 2; st++) {
    float li = rl[st];
    li += __shfl_xor(li, 16);
    li += __shfl_xor(li, 32);
    const float inv = 1.f / fmaxf(li, 1e-35f);
    const size_t orow = (qrow0 + w * 32 + st * 16 + l16) * D_ + hc;
    #pragma unroll
    for (int dt = 0; dt < 4; dt++) {
      const float4 o = {Ot[st][dt][0] * inv, Ot[st][dt][1] * inv,
                        Ot[st][dt][2] * inv, Ot[st][dt][3] * inv};
      *(float4*)&out[orow + dt * 16 + quad * 4] = o;
    }
  }
}

extern "C" void kernel_launch(void* const* d_in, const int* in_sizes, int n_in,
                              void* d_out, int out_size, void* d_ws, size_t ws_size,
                              hipStream_t stream) {
  const float* hs  = (const float*)d_in[0];
  const int*   msk = (const int*)d_in[1];
  const float* Wq  = (const float*)d_in[2];
  const float* bq  = (const float*)d_in[3];
  const float* Wk  = (const float*)d_in[4];
  const float* bk  = (const float*)d_in[5];
  float* out = (float*)d_out;

  unsigned short* QT  = (unsigned short*)d_ws;             // [H*64][M_]  8 MB
  unsigned short* K2b = QT  + (size_t)D_ * M_;             // [M_][D_]    8 MB
  unsigned short* WqT = K2b + (size_t)M_ * D_;             // [D_][D_]    2 MB
  unsigned short* WkT = WqT + (size_t)D_ * D_;             // [D_][D_]    2 MB
  unsigned short* hsb = WkT + (size_t)D_ * D_;             // [M_][D_]    8 MB

  prep_hs<<<1024, 256, 0, stream>>>(hs, hsb);
  prep_w<<<dim3(D_ / 64, D_ / 64, 2), 256, 0, stream>>>(Wq, Wk, WqT, WkT);
  proj_kernel<<<dim3(M_ / 128, D_ / 64), 256, 0, stream>>>(hsb, WqT, WkT, bq, bk, K2b, QT);
  attn_kernel<<<dim3(B_ * H_, S_ / 64), 128, 0, stream>>>(QT, K2b, msk, out);
}

// Round 8
// 196.540 us; speedup vs baseline: 1.4149x; 1.4149x over previous
//
#include <hip/hip_runtime.h>
#include <hip/hip_bf16.h>
#include <math.h>

#define B_  2
#define S_  2048
#define D_  1024
#define H_  16
#define DH_ 64
#define M_  (B_ * S_)   // 4096 tokens

typedef __attribute__((ext_vector_type(8))) short bf16x8;  // 8 bf16 (4 VGPRs)
typedef __attribute__((ext_vector_type(4))) float f32x4;   // MFMA C/D frag

#if __has_builtin(__builtin_amdgcn_global_load_lds)
#define HAVE_GLL 1
#else
#define HAVE_GLL 0
#endif

__device__ __forceinline__ float fast_exp2(float x) {
  return __builtin_amdgcn_exp2f(x);   // v_exp_f32
}

__device__ __forceinline__ unsigned short f2bf(float f) {
  union { float f; unsigned u; } c; c.f = f;
  unsigned u = c.u;
  return (unsigned short)((u + 0x7FFFu + ((u >> 16) & 1u)) >> 16);  // RNE
}

// pack two floats -> two bf16 (round-half-up) in one dword via v_perm
__device__ __forceinline__ unsigned pkbf(float lo, float hi) {
  union { float f; unsigned u; } a, b;
  a.f = lo; b.f = hi;
  return __builtin_amdgcn_perm(b.u + 0x8000u, a.u + 0x8000u, 0x07060302u);
}

__device__ __forceinline__ float logsig(float x) {
  return fminf(x, 0.f) - log1pf(__expf(-fabsf(x)));   // stable log_sigmoid
}

// ---------------------------------------------------------------------------
// Kernel 0a: hs fp32 [M][D] -> bf16 hsb (streaming, coalesced)
// ---------------------------------------------------------------------------
__global__ __launch_bounds__(256) void prep_hs(
    const float* __restrict__ hs, unsigned short* __restrict__ hsb)
{
  const int nvec = M_ * D_ / 4;
  for (int i = blockIdx.x * 256 + threadIdx.x; i < nvec; i += gridDim.x * 256) {
    const float4 v = *(const float4*)&hs[(size_t)i * 4];
    uint2 u;
    u.x = pkbf(v.x, v.y);
    u.y = pkbf(v.z, v.w);
    *(uint2*)&hsb[(size_t)i * 4] = u;
  }
}

// ---------------------------------------------------------------------------
// Kernel 0b: transpose Wq/Wk (fp32 [K][N]) -> bf16 W^T [N][K]
// ---------------------------------------------------------------------------
__global__ __launch_bounds__(256) void prep_w(
    const float* __restrict__ Wq, const float* __restrict__ Wk,
    unsigned short* __restrict__ WqT, unsigned short* __restrict__ WkT)
{
  __shared__ unsigned short T[64][72];
  const int tid = threadIdx.x;
  const int k0 = blockIdx.x * 64;
  const int n0 = blockIdx.y * 64;
  const float* W = blockIdx.z ? Wk : Wq;
  unsigned short* WT = blockIdx.z ? WkT : WqT;

  const int kr = tid >> 2, nc = (tid & 3) * 16;
  #pragma unroll
  for (int i = 0; i < 4; i++) {
    const float4 v = *(const float4*)&W[(size_t)(k0 + kr) * D_ + n0 + nc + i * 4];
    T[nc + i * 4 + 0][kr] = f2bf(v.x);
    T[nc + i * 4 + 1][kr] = f2bf(v.y);
    T[nc + i * 4 + 2][kr] = f2bf(v.z);
    T[nc + i * 4 + 3][kr] = f2bf(v.w);
  }
  __syncthreads();
  const int nr = tid >> 2, kc = (tid & 3) * 16;
  const uint4 a = *(const uint4*)&T[nr][kc];
  const uint4 b = *(const uint4*)&T[nr][kc + 8];
  *(uint4*)&WT[(size_t)(n0 + nr) * D_ + k0 + kc] = a;
  *(uint4*)&WT[(size_t)(n0 + nr) * D_ + k0 + kc + 8] = b;
}

// ---------------------------------------------------------------------------
// Kernel 1: Q = hs@Wq+bq ; K2 = logsig(logsig(Q)+Q+hs@Wk+bk)
//   outputs: K2b [M][D] bf16 row-major, QT [H*64][M] bf16 (per-head Q^T)
// m97-style staging: global_load_lds width=16 into UNPADDED row-major LDS
// ([row][64] bf16; wave-uniform dst + lane*16B). B-tile = merged [Wq;Wk]
// (rows 0..63 = Wq cols n0.., rows 64..127 = Wk same cols). Compute loop and
// epilogue identical to the R4 proj (best prior baseline).
// ---------------------------------------------------------------------------
__global__ __launch_bounds__(256) void proj_kernel(
    const unsigned short* __restrict__ hsb,
    const unsigned short* __restrict__ WqT, const unsigned short* __restrict__ WkT,
    const float* __restrict__ bqv, const float* __restrict__ bkv,
    unsigned short* __restrict__ K2b, unsigned short* __restrict__ QT)
{
  __shared__ unsigned short SM[16384];   // 32 KB
  unsigned short* Ash = SM;              // [128][64] hs tile (row-major)
  unsigned short* Bsh = SM + 8192;       // [128][64] merged Wq(0..63)/Wk(64..127)

  const int tid  = threadIdx.x;
  const int w    = tid >> 6;
  const int lane = tid & 63;
  const int quad = lane >> 4;
  const int l16  = lane & 15;
  const int m0 = blockIdx.x * 128;
  const int n0 = blockIdx.y * 64;     // = head * 64

  float bqs[4], bks[4];
  #pragma unroll
  for (int nt = 0; nt < 4; nt++) {
    bqs[nt] = bqv[n0 + nt * 16 + l16];
    bks[nt] = bkv[n0 + nt * 16 + l16];
  }

  f32x4 accQ[2][4], accK[2][4];
  #pragma unroll
  for (int st = 0; st < 2; st++)
    #pragma unroll
    for (int nt = 0; nt < 4; nt++) {
      accQ[st][nt] = (f32x4){0.f, 0.f, 0.f, 0.f};
      accK[st][nt] = (f32x4){0.f, 0.f, 0.f, 0.f};
    }

  // staging: wave v, call j -> 1 KB chunk = 8 rows; lane covers
  // row = base + lane/8, col = (lane%8)*8  (matches dst + lane*16B)
  const int srow8 = lane >> 3;          // 0..7
  const int scol  = (lane & 7) * 8;     // 0..56

  const unsigned short* agp[4];
  const unsigned short* bgp[4];
  unsigned short* aldst[4];
  unsigned short* bldst[4];
  #pragma unroll
  for (int j = 0; j < 4; j++) {
    const int arow = w * 32 + j * 8 + srow8;          // 0..127
    agp[j]   = hsb + (size_t)(m0 + arow) * D_ + scol;
    aldst[j] = Ash + (w * 32 + j * 8) * 64;           // wave-uniform
    const int brow = w * 32 + j * 8 + srow8;          // 0..127
    const unsigned short* bsrc = (w * 32 + j * 8 < 64)
        ? WqT + (size_t)(n0 + brow) * D_
        : WkT + (size_t)(n0 + brow - 64) * D_;
    bgp[j]   = bsrc + scol;
    bldst[j] = Bsh + (w * 32 + j * 8) * 64;           // wave-uniform
  }

  for (int k0 = 0; k0 < D_; k0 += 64) {
    __syncthreads();   // previous tile fully consumed
#if HAVE_GLL
    #pragma unroll
    for (int j = 0; j < 4; j++)
      __builtin_amdgcn_global_load_lds(
          (const __attribute__((address_space(1))) unsigned int*)(agp[j] + k0),
          (__attribute__((address_space(3))) unsigned int*)aldst[j], 16, 0, 0);
    #pragma unroll
    for (int j = 0; j < 4; j++)
      __builtin_amdgcn_global_load_lds(
          (const __attribute__((address_space(1))) unsigned int*)(bgp[j] + k0),
          (__attribute__((address_space(3))) unsigned int*)bldst[j], 16, 0, 0);
#else
    #pragma unroll
    for (int j = 0; j < 4; j++)
      *(uint4*)(aldst[j] + (size_t)lane * 8) = *(const uint4*)(agp[j] + k0);
    #pragma unroll
    for (int j = 0; j < 4; j++)
      *(uint4*)(bldst[j] + (size_t)lane * 8) = *(const uint4*)(bgp[j] + k0);
#endif
    __syncthreads();   // drains the async loads (vmcnt before s_barrier)

    #pragma unroll
    for (int kk = 0; kk < 2; kk++) {
      bf16x8 af[2];
      af[0] = *(const bf16x8*)&Ash[(w * 32 + l16) * 64 + kk * 32 + quad * 8];
      af[1] = *(const bf16x8*)&Ash[(w * 32 + 16 + l16) * 64 + kk * 32 + quad * 8];
      #pragma unroll
      for (int nt = 0; nt < 4; nt++) {
        const bf16x8 bq8 = *(const bf16x8*)&Bsh[(nt * 16 + l16) * 64 + kk * 32 + quad * 8];
        const bf16x8 bk8 = *(const bf16x8*)&Bsh[(64 + nt * 16 + l16) * 64 + kk * 32 + quad * 8];
        accQ[0][nt] = __builtin_amdgcn_mfma_f32_16x16x32_bf16(af[0], bq8, accQ[0][nt], 0, 0, 0);
        accQ[1][nt] = __builtin_amdgcn_mfma_f32_16x16x32_bf16(af[1], bq8, accQ[1][nt], 0, 0, 0);
        accK[0][nt] = __builtin_amdgcn_mfma_f32_16x16x32_bf16(af[0], bk8, accK[0][nt], 0, 0, 0);
        accK[1][nt] = __builtin_amdgcn_mfma_f32_16x16x32_bf16(af[1], bk8, accK[1][nt], 0, 0, 0);
      }
    }
  }

  __syncthreads();   // K-loop done; reuse SM as Qt [64 d][136 m]
  unsigned short* Qt = SM;   // 64*136 = 8704 <= 16384
  #pragma unroll
  for (int st = 0; st < 2; st++) {
    #pragma unroll
    for (int nt = 0; nt < 4; nt++) {
      float qv[4];
      #pragma unroll
      for (int r = 0; r < 4; r++) {
        const float q  = accQ[st][nt][r] + bqs[nt];
        const float kr = accK[st][nt][r] + bks[nt];
        const float k2 = logsig(logsig(q) + q + kr);
        const int m = m0 + w * 32 + st * 16 + quad * 4 + r;
        K2b[(size_t)m * D_ + n0 + nt * 16 + l16] = f2bf(k2);
        qv[r] = q;
      }
      const ushort4 qu = {f2bf(qv[0]), f2bf(qv[1]), f2bf(qv[2]), f2bf(qv[3])};
      *(ushort4*)&Qt[(nt * 16 + l16) * 136 + w * 32 + st * 16 + quad * 4] = qu;
    }
  }
  __syncthreads();
  {
    const int dr = tid >> 2, mc = (tid & 3) * 32;
    #pragma unroll
    for (int i = 0; i < 4; i++) {
      const uint4 v = *(const uint4*)&Qt[dr * 136 + mc + i * 8];
      *(uint4*)&QT[(size_t)(n0 + dr) * M_ + m0 + mc + i * 8] = v;
    }
  }
}

// ---------------------------------------------------------------------------
// Kernel 2: flash attention — EXACT R4 structure (best measured: 70 us).
// S^T formulation, fixed-shift softmax, Psh LDS round-trip for PV,
// padded-72 LDS, qt-fastest grid, 256 threads.
// ---------------------------------------------------------------------------
__global__ __launch_bounds__(256) void attn_kernel(
    const unsigned short* __restrict__ QT,
    const unsigned short* __restrict__ K2b,
    const int* __restrict__ mask,
    float* __restrict__ out)
{
  __shared__ unsigned short Qa [128][72];  // Q [q][d]
  __shared__ unsigned short K2s[64][72];   // K2 [key][d]
  __shared__ unsigned short Vt [64][72];   // V^T [d][key]
  __shared__ unsigned short Psh[4][16][72];// per-wave P [q16][key64]

  const int tid  = threadIdx.x;
  const int w    = tid >> 6;
  const int lane = tid & 63;
  const int quad = lane >> 4;
  const int l16  = lane & 15;

  const int qt = blockIdx.x;          // 0..15
  const int bh = blockIdx.y;          // 0..31
  const int b = bh >> 4, h = bh & 15;
  const size_t qrow0 = (size_t)b * S_ + (size_t)qt * 128;
  const size_t krow0 = (size_t)b * S_;
  const size_t trow  = (size_t)h * 64;

  // stage Qa [q][d] from QT (once per block)
  {
    const int dr = tid >> 2, qc = (tid & 3) * 32;
    #pragma unroll
    for (int i = 0; i < 4; i++) {
      const uint4 v = *(const uint4*)&QT[(trow + dr) * M_ + qrow0 + qc + i * 8];
      const unsigned short* p = (const unsigned short*)&v;
      #pragma unroll
      for (int j = 0; j < 8; j++) Qa[qc + i * 8 + j][dr] = p[j];
    }
  }
  __syncthreads();

  bf16x8 qfrag[2][2];
  #pragma unroll
  for (int st = 0; st < 2; st++)
    #pragma unroll
    for (int kk = 0; kk < 2; kk++)
      qfrag[st][kk] = *(const bf16x8*)&Qa[w * 32 + st * 16 + l16][kk * 32 + quad * 8];

  // c2 = -(1/8)*log2(e)*msk ; fixed shift of 12 in exp2 domain
  float c2[2], rl[2] = {0.f, 0.f};
  #pragma unroll
  for (int st = 0; st < 2; st++)
    c2[st] = (mask[qrow0 + w * 32 + st * 16 + l16] != 0) ? -0.18033688f : 0.f;

  f32x4 Ot[2][4];
  #pragma unroll
  for (int st = 0; st < 2; st++)
    #pragma unroll
    for (int dt = 0; dt < 4; dt++) Ot[st][dt] = (f32x4){0.f, 0.f, 0.f, 0.f};

  for (int kt = 0; kt < S_ / 64; kt++) {
    __syncthreads();
    {
      const int rr = tid >> 2, cc = (tid & 3) * 16;
      const size_t kr = (krow0 + kt * 64 + rr) * D_ + trow + cc;
      *(uint4*)&K2s[rr][cc]     = *(const uint4*)&K2b[kr];
      *(uint4*)&K2s[rr][cc + 8] = *(const uint4*)&K2b[kr + 8];
      const size_t vr = (trow + rr) * M_ + krow0 + kt * 64 + cc;
      *(uint4*)&Vt[rr][cc]      = *(const uint4*)&QT[vr];
      *(uint4*)&Vt[rr][cc + 8]  = *(const uint4*)&QT[vr + 8];
    }
    __syncthreads();

    bf16x8 k2f[4][2], vf[4][2];
    #pragma unroll
    for (int nt = 0; nt < 4; nt++)
      #pragma unroll
      for (int kk = 0; kk < 2; kk++) {
        k2f[nt][kk] = *(const bf16x8*)&K2s[nt * 16 + l16][kk * 32 + quad * 8];
        vf[nt][kk]  = *(const bf16x8*)&Vt [nt * 16 + l16][kk * 32 + quad * 8];
      }

    #pragma unroll
    for (int st = 0; st < 2; st++) {
      f32x4 sc[4];
      #pragma unroll
      for (int nt = 0; nt < 4; nt++) sc[nt] = (f32x4){0.f, 0.f, 0.f, 0.f};
      #pragma unroll
      for (int kk = 0; kk < 2; kk++)
        #pragma unroll
        for (int nt = 0; nt < 4; nt++)
          sc[nt] = __builtin_amdgcn_mfma_f32_16x16x32_bf16(k2f[nt][kk], qfrag[st][kk], sc[nt], 0, 0, 0);

      // p = exp2(c2*sc - 12); accumulate row-sum; pack pairs -> Psh
      #pragma unroll
      for (int nt = 0; nt < 4; nt++) {
        const float p0 = fast_exp2(fmaf(sc[nt][0], c2[st], -12.f));
        const float p1 = fast_exp2(fmaf(sc[nt][1], c2[st], -12.f));
        const float p2 = fast_exp2(fmaf(sc[nt][2], c2[st], -12.f));
        const float p3 = fast_exp2(fmaf(sc[nt][3], c2[st], -12.f));
        rl[st] += (p0 + p1) + (p2 + p3);
        const uint2 pk = {pkbf(p0, p1), pkbf(p2, p3)};
        *(uint2*)&Psh[w][l16][nt * 16 + quad * 4] = pk;
      }

      #pragma unroll
      for (int kk = 0; kk < 2; kk++) {
        const bf16x8 pf = *(const bf16x8*)&Psh[w][l16][kk * 32 + quad * 8];
        #pragma unroll
        for (int dt = 0; dt < 4; dt++)
          Ot[st][dt] = __builtin_amdgcn_mfma_f32_16x16x32_bf16(vf[dt][kk], pf, Ot[st][dt], 0, 0, 0);
      }
    }
  }

  // final row-sum across quads, then write O^T / l
  #pragma unroll
  for (int st = 0; st < 2; st++) {
    float li = rl[st];
    li += __shfl_xor(li, 16);
    li += __shfl_xor(li, 32);
    const float inv = 1.f / fmaxf(li, 1e-35f);
    const size_t orow = (qrow0 + w * 32 + st * 16 + l16) * D_ + trow;
    #pragma unroll
    for (int dt = 0; dt < 4; dt++) {
      const float4 o = {Ot[st][dt][0] * inv, Ot[st][dt][1] * inv,
                        Ot[st][dt][2] * inv, Ot[st][dt][3] * inv};
      *(float4*)&out[orow + dt * 16 + quad * 4] = o;
    }
  }
}

extern "C" void kernel_launch(void* const* d_in, const int* in_sizes, int n_in,
                              void* d_out, int out_size, void* d_ws, size_t ws_size,
                              hipStream_t stream) {
  const float* hs  = (const float*)d_in[0];
  const int*   msk = (const int*)d_in[1];
  const float* Wq  = (const float*)d_in[2];
  const float* bq  = (const float*)d_in[3];
  const float* Wk  = (const float*)d_in[4];
  const float* bk  = (const float*)d_in[5];
  float* out = (float*)d_out;

  unsigned short* QT  = (unsigned short*)d_ws;             // [H*64][M_]  8 MB
  unsigned short* K2b = QT  + (size_t)D_ * M_;             // [M_][D_]    8 MB
  unsigned short* WqT = K2b + (size_t)M_ * D_;             // [D_][D_]    2 MB
  unsigned short* WkT = WqT + (size_t)D_ * D_;             // [D_][D_]    2 MB
  unsigned short* hsb = WkT + (size_t)D_ * D_;             // [M_][D_]    8 MB

  prep_hs<<<1024, 256, 0, stream>>>(hs, hsb);
  prep_w<<<dim3(D_ / 64, D_ / 64, 2), 256, 0, stream>>>(Wq, Wk, WqT, WkT);
  proj_kernel<<<dim3(M_ / 128, D_ / 64), 256, 0, stream>>>(hsb, WqT, WkT, bq, bk, K2b, QT);
  attn_kernel<<<dim3(S_ / 128, B_ * H_), 256, 0, stream>>>(QT, K2b, msk, out);
}